// Round 19
// baseline (107.059 us; speedup 1.0000x reference)
//
#include <hip/hip_runtime.h>
#include <hip/hip_bf16.h>

// MultiHeadAttention fused pipeline, round 18.
// B=2 S=2048 D=1024 H=16 dk=64.
// ws layout (48 MB): Xb 8M | Wqkv bf16 6M | Wo 2M | Qb 8M | Kb 8M | Vt 8M | Ob 8M
// Changes vs R17:
//  - gemm_qkv: re-tiled 256x256 -> 256x192 => 16m x 16n = 256 blocks = exactly
//    1 block/CU (was 192/256 = 75% CU coverage). Parameter-level change to the
//    verified 8-phase template: per-wave 128x48 (acc[8][3]), B-stage 3 GLLs,
//    LDS 112KB. Epilogue handles Q|K|V boundary per 16-col fragment (16-aligned,
//    z uniform per nf). Per-CU work 0.75x of previous per-block wall.
//  - attn (R6, 48us), gemm_out (R13 2-phase), casts: unchanged.

typedef unsigned short u16;
typedef __attribute__((ext_vector_type(4))) unsigned short u16x4;
typedef __attribute__((ext_vector_type(8))) short short8;   // 8 x bf16 (4 VGPRs)
typedef __attribute__((ext_vector_type(4))) float f32x4;

__device__ __forceinline__ u16 f2bf(float f) {  // native RNE f32->bf16
  __bf16 b = (__bf16)f;
  return __builtin_bit_cast(unsigned short, b);
}

__device__ __forceinline__ f32x4 mfma_bf16(short8 a, short8 b, f32x4 c) {
  return __builtin_amdgcn_mfma_f32_16x16x32_bf16(a, b, c, 0, 0, 0);
}

#define GLL16(gp, lp) __builtin_amdgcn_global_load_lds( \
    (const __attribute__((address_space(1))) void*)(gp), \
    (__attribute__((address_space(3))) void*)(lp), 16, 0, 0)

#define QSCALE 0.18033688011112042f   /* 0.125 * log2(e) */

// ---------------------------------------------------------------- casts
__global__ __launch_bounds__(256) void cast_all(
    const float* __restrict__ x,
    const float* __restrict__ wq, const float* __restrict__ wk,
    const float* __restrict__ wv, const float* __restrict__ wo,
    u16* __restrict__ xb, u16* __restrict__ wpanel)
{
  int i = blockIdx.x * 256 + threadIdx.x;
  const float* s; u16x4* d;
  if (i < 1048576) {
    s = x; d = (u16x4*)xb + i;
  } else {
    int j = i - 1048576;
    int w = j >> 18;                       // 0..3
    const float* ws4 = (w == 0) ? wq : (w == 1) ? wk : (w == 2) ? wv : wo;
    s = ws4; d = (u16x4*)wpanel + j;
    i = j & 262143;
  }
  float4 v = ((const float4*)s)[i];
  u16x4 o; o[0] = f2bf(v.x); o[1] = f2bf(v.y); o[2] = f2bf(v.z); o[3] = f2bf(v.w);
  *d = o;
}

// ------------------------------------------------ fused QKV, 256x192 8-phase
// A = Xb [4096][1024], B = Wqkv [3072][1024]. C = A*B^T.
// 512 thr = 8 waves: wave w -> (wr=w>>2, wcn=w&3); out rows wr*128..+128,
// cols wcn*48..+48 => acc[8][3]. BK=64, 16 K-tiles, 4 phases each.
// LDS: A 2x[256][64] (64KB) + B 2x[192][64] (48KB) = 112KB, XOR-swizzled slots.
__global__ __launch_bounds__(512, 2) void gemm_qkv(
    const u16* __restrict__ X, const u16* __restrict__ Wqkv,
    const float* __restrict__ bq, const float* __restrict__ bk, const float* __restrict__ bv,
    u16* __restrict__ Qo, u16* __restrict__ Ko, u16* __restrict__ Vt)
{
  __shared__ u16 smem[57344];                    // 112 KB
  u16* const sA0 = smem;                         // [256][64]
  u16* const sA1 = smem + 16384;
  u16* const sB0 = smem + 32768;                 // [192][64]
  u16* const sB1 = smem + 45056;

  const int tid = threadIdx.x, lane = tid & 63, w = tid >> 6;
  const int wr = w >> 2, wcn = w & 3;
  const int rl = lane & 15, g = lane >> 4, rsw = rl & 7;

  const int bflat = blockIdx.x;                  // 256 = 8 XCD * 32
  const int xcd = bflat & 7, idx = bflat >> 3;   // idx 0..31
  const int mt = xcd * 2 + (idx & 1);            // 16 m-tiles, 2 per XCD
  const int nt = idx >> 1;                       // 16 n-tiles of 192
  const int m0 = mt * 256;

  const int lr = lane >> 3, lc = lane & 7;
  const size_t srcoff = (size_t)(w * 8 + lr) * 1024 + ((lc ^ lr) * 8);
  const u16* gaS = X    + (size_t)m0 * 1024 + srcoff;
  const u16* gbS = Wqkv + (size_t)(nt * 192) * 1024 + srcoff;

  f32x4 acc[8][3];
#pragma unroll
  for (int mf = 0; mf < 8; ++mf)
#pragma unroll
    for (int nf = 0; nf < 3; ++nf) acc[mf][nf] = (f32x4){0.f, 0.f, 0.f, 0.f};

  auto loadA = [&](const u16* buf, int mf, int kh) -> short8 {
    return *(const short8*)&buf[(wr * 128 + mf * 16 + rl) * 64 +
                                (((kh * 4 + g) ^ rsw) * 8)];
  };
  auto loadB = [&](const u16* buf, int nf, int kh) -> short8 {
    return *(const short8*)&buf[(wcn * 48 + nf * 16 + rl) * 64 +
                                (((kh * 4 + g) ^ rsw) * 8)];
  };

  // one K-tile = 4 phases; stage halves of tile ts into stA/stB in ph0/ph1
  auto proc_tile = [&](const u16* bufA, const u16* bufB,
                       u16* stA, u16* stB, int ts, bool doSt) {
    short8 af[4], bf[3];
    // phase 0: stage A(next, 4 GLL) | B(kh0) + A(mf0-3,kh0) | 12 MFMA
    if (doSt) {
#pragma unroll
      for (int i = 0; i < 4; ++i)
        GLL16(gaS + (size_t)(i * 64) * 1024 + ts * 64, stA + (i * 64 + w * 8) * 64);
    }
#pragma unroll
    for (int nf = 0; nf < 3; ++nf) bf[nf] = loadB(bufB, nf, 0);
#pragma unroll
    for (int i = 0; i < 4; ++i) af[i] = loadA(bufA, i, 0);
    __builtin_amdgcn_s_setprio(1);
#pragma unroll
    for (int i = 0; i < 4; ++i)
#pragma unroll
      for (int nf = 0; nf < 3; ++nf)
        acc[i][nf] = mfma_bf16(af[i], bf[nf], acc[i][nf]);
    __builtin_amdgcn_s_setprio(0);
    __builtin_amdgcn_s_barrier();
    // phase 1: stage B(next, 3 GLL) | A(mf4-7,kh0) | 12 MFMA
    if (doSt) {
#pragma unroll
      for (int i = 0; i < 3; ++i)
        GLL16(gbS + (size_t)(i * 64) * 1024 + ts * 64, stB + (i * 64 + w * 8) * 64);
    }
#pragma unroll
    for (int i = 0; i < 4; ++i) af[i] = loadA(bufA, 4 + i, 0);
    __builtin_amdgcn_s_setprio(1);
#pragma unroll
    for (int i = 0; i < 4; ++i)
#pragma unroll
      for (int nf = 0; nf < 3; ++nf)
        acc[4 + i][nf] = mfma_bf16(af[i], bf[nf], acc[4 + i][nf]);
    __builtin_amdgcn_s_setprio(0);
    __builtin_amdgcn_s_barrier();
    // phase 2: B(kh1) + A(mf0-3,kh1) | 12 MFMA
#pragma unroll
    for (int nf = 0; nf < 3; ++nf) bf[nf] = loadB(bufB, nf, 1);
#pragma unroll
    for (int i = 0; i < 4; ++i) af[i] = loadA(bufA, i, 1);
    __builtin_amdgcn_s_setprio(1);
#pragma unroll
    for (int i = 0; i < 4; ++i)
#pragma unroll
      for (int nf = 0; nf < 3; ++nf)
        acc[i][nf] = mfma_bf16(af[i], bf[nf], acc[i][nf]);
    __builtin_amdgcn_s_setprio(0);
    __builtin_amdgcn_s_barrier();
    // phase 3: A(mf4-7,kh1) | 12 MFMA
#pragma unroll
    for (int i = 0; i < 4; ++i) af[i] = loadA(bufA, 4 + i, 1);
    __builtin_amdgcn_s_setprio(1);
#pragma unroll
    for (int i = 0; i < 4; ++i)
#pragma unroll
      for (int nf = 0; nf < 3; ++nf)
        acc[4 + i][nf] = mfma_bf16(af[i], bf[nf], acc[4 + i][nf]);
    __builtin_amdgcn_s_setprio(0);
  };

  // prologue: stage tile 0 into buf0
#pragma unroll
  for (int i = 0; i < 4; ++i)
    GLL16(gaS + (size_t)(i * 64) * 1024, sA0 + (i * 64 + w * 8) * 64);
#pragma unroll
  for (int i = 0; i < 3; ++i)
    GLL16(gbS + (size_t)(i * 64) * 1024, sB0 + (i * 64 + w * 8) * 64);
  __syncthreads();

#pragma unroll 1
  for (int tt = 0; tt < 8; ++tt) {
    proc_tile(sA0, sB0, sA1, sB1, 2 * tt + 1, true);
    __syncthreads();
    proc_tile(sA1, sB1, sA0, sB0, 2 * tt + 2, tt < 7);
    __syncthreads();
  }

  // -------- epilogue: per 16-col fragment, z = colg>>10 (uniform: 16-aligned)
  const int rg = g * 4;
#pragma unroll
  for (int nf = 0; nf < 3; ++nf) {
    const int colg = nt * 192 + wcn * 48 + nf * 16 + rl;   // 0..3071
    const int zc = colg >> 10;                             // 0=Q 1=K 2=V
    const int colp = colg & 1023;
    if (zc == 0) {
      float bb = bq[colp];
#pragma unroll
      for (int mf = 0; mf < 8; ++mf) {
        int row0 = m0 + wr * 128 + mf * 16 + rg;
#pragma unroll
        for (int r = 0; r < 4; ++r)
          Qo[(size_t)(row0 + r) * 1024 + colp] = f2bf((acc[mf][nf][r] + bb) * QSCALE);
      }
    } else if (zc == 1) {
      float bb = bk[colp];
#pragma unroll
      for (int mf = 0; mf < 8; ++mf) {
        int row0 = m0 + wr * 128 + mf * 16 + rg;
#pragma unroll
        for (int r = 0; r < 4; ++r)
          Ko[(size_t)(row0 + r) * 1024 + colp] = f2bf(acc[mf][nf][r] + bb);
      }
    } else {
      float bb = bv[colp];
#pragma unroll
      for (int mf = 0; mf < 8; ++mf) {
        int row0 = m0 + wr * 128 + mf * 16 + rg;       // b*2048 + s
        int bidx = row0 >> 11, sl = row0 & 2047;
        u16x4 pk;
#pragma unroll
        for (int r = 0; r < 4; ++r) pk[r] = f2bf(acc[mf][nf][r] + bb);
        *(u16x4*)&Vt[((size_t)(bidx * 1024 + colp)) * 2048 + sl] = pk;
      }
    }
  }
}

// Output projection: out(fp32) = Ob @ Wo^T + bo. 64x128 tiles -> 512 blocks
// (2 blocks/CU); xcd = b&7 owns m-tiles {8x..8x+7} (R13-proven version).
__global__ __launch_bounds__(256) void gemm_out(
    const u16* __restrict__ Ob, const u16* __restrict__ Wob,
    const float* __restrict__ bo, float* __restrict__ Out)
{
  __shared__ u16 sA[2048], sB[4096];
  const int bflat = blockIdx.x;
  const int xcd = bflat & 7, idx = bflat >> 3;      // idx 0..63
  const int m0 = (xcd * 8 + (idx & 7)) * 64;
  const int n0 = (idx >> 3) * 128;

  const int tid = threadIdx.x, lane = tid & 63, wave = tid >> 6;
  const int wr = wave >> 1, wc = wave & 1;
  const u16* ga = Ob  + (size_t)(m0 + (tid >> 2)) * 1024 + (tid & 3) * 8;
  const u16* gb = Wob + (size_t)(n0 + (tid >> 2)) * 1024 + (tid & 3) * 8;
  u16* la0 = sA + wave * 512;
  u16* lb0 = sB + wave * 512;          u16* lb1 = sB + 2048 + wave * 512;
  const int rl = lane & 15, kg = (lane >> 4) * 8, rg = (lane >> 4) * 4;

  f32x4 acc[2][4];
#pragma unroll
  for (int m = 0; m < 2; ++m)
#pragma unroll
    for (int n = 0; n < 4; ++n) acc[m][n] = (f32x4){0.f, 0.f, 0.f, 0.f};

  for (int k0 = 0; k0 < 1024; k0 += 32) {
    GLL16(ga + k0,             la0);   // A 64x32 (rows tid>>2)
    GLL16(gb + k0,             lb0);   // B rows 0..63
    GLL16(gb + 64 * 1024 + k0, lb1);   // B rows 64..127
    __syncthreads();
    short8 af[2], bf_[4];
#pragma unroll
    for (int m = 0; m < 2; ++m) af[m]  = *(const short8*)&sA[(wr * 32 + m * 16 + rl) * 32 + kg];
#pragma unroll
    for (int n = 0; n < 4; ++n) bf_[n] = *(const short8*)&sB[(wc * 64 + n * 16 + rl) * 32 + kg];
#pragma unroll
    for (int m = 0; m < 2; ++m)
#pragma unroll
      for (int n = 0; n < 4; ++n)
        acc[m][n] = mfma_bf16(af[m], bf_[n], acc[m][n]);
    __syncthreads();
  }

#pragma unroll
  for (int n = 0; n < 4; ++n) {
    int col = n0 + wc * 64 + n * 16 + rl;
    float bb = bo[col];
#pragma unroll
    for (int m = 0; m < 2; ++m) {
      int row0 = m0 + wr * 32 + m * 16 + rg;
#pragma unroll
      for (int r = 0; r < 4; ++r)
        Out[(size_t)(row0 + r) * 1024 + col] = acc[m][n][r] + bb;
    }
  }
}

// ---------------------------------------------------------------- flash attention
// R6 kernel exact (proven 48.0us, 0 bank conflicts). Swapped QK^T (mfma(K,Q));
// K rows read PERMUTED from LDS so score C-regs match PV B-operand k-order;
// Q pre-scaled by 0.125*log2e. K/V staged per 64-key tile into double-buffered
// XOR-swizzled LDS via global_load_lds. Wave = 16 q rows; block = 8 waves
// (512 thr); grid = 512; XCD x owns bh {4x..4x+3} (2MB K/V in its L2).
__global__ __launch_bounds__(512) void attn_fwd(
    const u16* __restrict__ Q, const u16* __restrict__ K,
    const u16* __restrict__ Vt, u16* __restrict__ O)
{
  __shared__ u16 sK[2][64][64];   // [buf][key row][d elems], elem-swizzled
  __shared__ u16 sV[2][64][64];   // [buf][d row][key elems], elem-swizzled

  const int tid = threadIdx.x, lane = tid & 63, wave = tid >> 6;  // wave 0..7
  const int rl = lane & 15, g = lane >> 4;

  const int bflat = blockIdx.x;
  const int xcd = bflat & 7, j = bflat >> 3;        // 512 = 8 XCD * 64
  const int bh = xcd * 4 + (j >> 4);                // 4 bh per XCD (2MB in L2)
  const int qchunk = j & 15;
  const int b = bh >> 4, h = bh & 15;
  const int qbase = qchunk * 128 + wave * 16;

  const u16* Qp = Q + (size_t)(b * 2048 + qbase) * 1024 + h * 64;
  const u16* Kp = K + (size_t)(b * 2048) * 1024 + h * 64;
  const u16* Vp = Vt + (size_t)(bh * 64) * 2048;

  short8 qf[2];
#pragma unroll
  for (int hf = 0; hf < 2; ++hf)
    qf[hf] = *(const short8*)&Qp[(size_t)rl * 1024 + hf * 32 + g * 8];

  const int keyperm = 8 * (rl >> 2) + (rl & 3);
  // K read swizzle (elements): swzK(r) = (r&3)|(((r>>3)&1)<<2); r bits from rl only
  const int swzK8 = (((rl & 3) | (((rl >> 2) & 1) << 2))) * 8;
  // V read swizzle: swzV(r) = r&7 with r = dg*16+rl -> rl&7
  const int swzV8 = (rl & 7) * 8;

  // staging address precompute (thread-constant); chunk = wave (0..7)
  const int srow = lane >> 3;                       // row within 8-row chunk
  const int feK = (((lane & 7) ^ (srow & 3)) * 8) ^ ((wave & 1) * 32);
  const int feV = (((lane & 7) ^ srow) * 8);

  f32x4 oacc[4];
  f32x4 lacc = (f32x4){0.f, 0.f, 0.f, 0.f};
#pragma unroll
  for (int dg = 0; dg < 4; ++dg) oacc[dg] = (f32x4){0.f, 0.f, 0.f, 0.f};
  float mrun = -INFINITY;

  const short8 ONES = {0x3F80, 0x3F80, 0x3F80, 0x3F80,
                       0x3F80, 0x3F80, 0x3F80, 0x3F80};  // bf16 1.0 x8

  // stage one 64-key tile (K 8KB + V 8KB) into buffer nb; 1 GLL each per thread
  auto stage = [&](int nb, int kt) {
    const int grow = wave * 8 + srow;               // 0..63
    GLL16(Kp + (size_t)(kt + grow) * 1024 + feK, &sK[nb][wave * 8][0]);
    GLL16(Vp + (size_t)grow * 2048 + kt + feV,   &sV[nb][wave * 8][0]);
  };

  // process one 32-key subtile from buffer nb
  auto proc_sub = [&](int nb, int sub) {
    short8 kf[2][2];
#pragma unroll
    for (int t = 0; t < 2; ++t) {
      const int r = sub * 32 + keyperm + 4 * t;
#pragma unroll
      for (int hf = 0; hf < 2; ++hf)
        kf[t][hf] = *(const short8*)&sK[nb][r][(hf * 32 + g * 8) ^ swzK8];
    }
    short8 vf[4];
#pragma unroll
    for (int dg = 0; dg < 4; ++dg)
      vf[dg] = *(const short8*)&sV[nb][dg * 16 + rl][(sub * 32 + g * 8) ^ swzV8];

    f32x4 sc[2];
    __builtin_amdgcn_s_setprio(1);
#pragma unroll
    for (int t = 0; t < 2; ++t) {
      f32x4 a = (f32x4){0.f, 0.f, 0.f, 0.f};
      a = mfma_bf16(kf[t][0], qf[0], a);
      a = mfma_bf16(kf[t][1], qf[1], a);
      sc[t] = a;
    }
    __builtin_amdgcn_s_setprio(0);

    float p2[8];
#pragma unroll
    for (int t = 0; t < 2; ++t)
#pragma unroll
      for (int r = 0; r < 4; ++r) p2[t * 4 + r] = sc[t][r];
    float a0 = fmaxf(fmaxf(p2[0], p2[1]), p2[2]);
    float a1 = fmaxf(fmaxf(p2[3], p2[4]), p2[5]);
    float a2 = fmaxf(p2[6], p2[7]);
    float tm = fmaxf(fmaxf(a0, a1), a2);
    // defer-max: rescale only when tile max grows past THR=8 (exp2 domain)
    if (!__all(tm <= mrun + 8.0f)) {
      tm = fmaxf(tm, __shfl_xor(tm, 16));
      tm = fmaxf(tm, __shfl_xor(tm, 32));
      float mnew = fmaxf(mrun, tm);
      float sfac = __builtin_amdgcn_exp2f(mrun - mnew);
      mrun = mnew;
#pragma unroll
      for (int dg = 0; dg < 4; ++dg)
#pragma unroll
        for (int r = 0; r < 4; ++r) oacc[dg][r] *= sfac;
      lacc[0] *= sfac;   // only reg 0 is ever read
    }
    short8 pb;
#pragma unroll
    for (int j2 = 0; j2 < 8; ++j2)
      pb[j2] = (short)f2bf(__builtin_amdgcn_exp2f(p2[j2] - mrun));

    __builtin_amdgcn_s_setprio(1);
    lacc = mfma_bf16(ONES, pb, lacc);   // row-sum on matrix pipe
#pragma unroll
    for (int dg = 0; dg < 4; ++dg)
      oacc[dg] = mfma_bf16(vf[dg], pb, oacc[dg]);
    __builtin_amdgcn_s_setprio(0);
  };

  // double-buffered main loop: 32 tiles of 64 keys, unrolled x2 (static nb)
  stage(0, 0);
  __syncthreads();
  for (int kt = 0; kt < 2048; kt += 128) {
    stage(1, kt + 64);
    proc_sub(0, 0);
    proc_sub(0, 1);
    __syncthreads();                     // buf1 staged; buf0 fully read
    if (kt + 128 < 2048) stage(0, kt + 128);
    proc_sub(1, 0);
    proc_sub(1, 1);
    __syncthreads();
  }

  float inv = 1.0f / lacc[0];
  int qrow = qbase + rl;
  u16* op = O + (size_t)(b * 2048 + qrow) * 1024 + h * 64;
#pragma unroll
  for (int dg = 0; dg < 4; ++dg) {
    u16x4 pk;
#pragma unroll
    for (int r = 0; r < 4; ++r) pk[r] = f2bf(oacc[dg][r] * inv);
    *(u16x4*)&op[dg * 16 + g * 4] = pk;
  }
}

// ---------------------------------------------------------------- launch
extern "C" void kernel_launch(void* const* d_in, const int* in_sizes, int n_in,
                              void* d_out, int out_size, void* d_ws, size_t ws_size,
                              hipStream_t stream) {
  const float* x  = (const float*)d_in[0];
  const float* Wq = (const float*)d_in[1];
  const float* bq = (const float*)d_in[2];
  const float* Wk = (const float*)d_in[3];
  const float* bk = (const float*)d_in[4];
  const float* Wv = (const float*)d_in[5];
  const float* bv = (const float*)d_in[6];
  const float* Wo = (const float*)d_in[7];
  const float* bo = (const float*)d_in[8];

  char* ws = (char*)d_ws;
  const size_t MB = 1024 * 1024;
  u16* Xb  = (u16*)(ws + 0 * MB);
  u16* Wqb = (u16*)(ws + 8 * MB);    // Wqkv|Wo: 4 contiguous 2MB panels
  u16* Wob = (u16*)(ws + 14 * MB);
  u16* Qb  = (u16*)(ws + 16 * MB);
  u16* Kb  = (u16*)(ws + 24 * MB);
  u16* Vtb = (u16*)(ws + 32 * MB);
  u16* Ob  = (u16*)(ws + 40 * MB);

  cast_all<<<dim3(8192), 256, 0, stream>>>(x, Wq, Wk, Wv, Wo, Xb, Wqb);
  gemm_qkv<<<dim3(256), 512, 0, stream>>>(Xb, Wqb, bq, bk, bv, Qb, Kb, Vtb);
  attn_fwd<<<dim3(512), 512, 0, stream>>>(Qb, Kb, Vtb, Ob);
  gemm_out<<<dim3(512), 256, 0, stream>>>(Ob, Wob, bo, (float*)d_out);
}

// Round 20
// 106.284 us; speedup vs baseline: 1.0073x; 1.0073x over previous
//
#include <hip/hip_runtime.h>
#include <hip/hip_bf16.h>

// MultiHeadAttention fused pipeline, round 18.
// B=2 S=2048 D=1024 H=16 dk=64.
// ws layout (48 MB): Xb 8M | Wqkv bf16 6M | Wo 2M | Qb 8M | Kb 8M | Vt 8M | Ob 8M
// Changes vs R17:
//  - gemm_qkv: re-tiled 256x256 -> 256x192 => 16m x 16n = 256 blocks = exactly
//    1 block/CU (was 192/256 = 75% CU coverage). Parameter-level change to the
//    verified 8-phase template: per-wave 128x48 (acc[8][3]), B-stage 3 GLLs,
//    LDS 112KB. Epilogue handles Q|K|V boundary per 16-col fragment (16-aligned,
//    z uniform per nf). Per-CU work 0.75x of previous per-block wall.
//  - attn (R6, 48us), gemm_out (R13 2-phase), casts: unchanged.

typedef unsigned short u16;
typedef __attribute__((ext_vector_type(4))) unsigned short u16x4;
typedef __attribute__((ext_vector_type(8))) short short8;   // 8 x bf16 (4 VGPRs)
typedef __attribute__((ext_vector_type(4))) float f32x4;

__device__ __forceinline__ u16 f2bf(float f) {  // native RNE f32->bf16
  __bf16 b = (__bf16)f;
  return __builtin_bit_cast(unsigned short, b);
}

__device__ __forceinline__ f32x4 mfma_bf16(short8 a, short8 b, f32x4 c) {
  return __builtin_amdgcn_mfma_f32_16x16x32_bf16(a, b, c, 0, 0, 0);
}

#define GLL16(gp, lp) __builtin_amdgcn_global_load_lds( \
    (const __attribute__((address_space(1))) void*)(gp), \
    (__attribute__((address_space(3))) void*)(lp), 16, 0, 0)

#define QSCALE 0.18033688011112042f   /* 0.125 * log2(e) */

// ---------------------------------------------------------------- casts
__global__ __launch_bounds__(256) void cast_all(
    const float* __restrict__ x,
    const float* __restrict__ wq, const float* __restrict__ wk,
    const float* __restrict__ wv, const float* __restrict__ wo,
    u16* __restrict__ xb, u16* __restrict__ wpanel)
{
  int i = blockIdx.x * 256 + threadIdx.x;
  const float* s; u16x4* d;
  if (i < 1048576) {
    s = x; d = (u16x4*)xb + i;
  } else {
    int j = i - 1048576;
    int w = j >> 18;                       // 0..3
    const float* ws4 = (w == 0) ? wq : (w == 1) ? wk : (w == 2) ? wv : wo;
    s = ws4; d = (u16x4*)wpanel + j;
    i = j & 262143;
  }
  float4 v = ((const float4*)s)[i];
  u16x4 o; o[0] = f2bf(v.x); o[1] = f2bf(v.y); o[2] = f2bf(v.z); o[3] = f2bf(v.w);
  *d = o;
}

// ------------------------------------------------ fused QKV, 256x192 8-phase
// A = Xb [4096][1024], B = Wqkv [3072][1024]. C = A*B^T.
// 512 thr = 8 waves: wave w -> (wr=w>>2, wcn=w&3); out rows wr*128..+128,
// cols wcn*48..+48 => acc[8][3]. BK=64, 16 K-tiles, 4 phases each.
// LDS: A 2x[256][64] (64KB) + B 2x[192][64] (48KB) = 112KB, XOR-swizzled slots.
__global__ __launch_bounds__(512, 2) void gemm_qkv(
    const u16* __restrict__ X, const u16* __restrict__ Wqkv,
    const float* __restrict__ bq, const float* __restrict__ bk, const float* __restrict__ bv,
    u16* __restrict__ Qo, u16* __restrict__ Ko, u16* __restrict__ Vt)
{
  __shared__ u16 smem[57344];                    // 112 KB
  u16* const sA0 = smem;                         // [256][64]
  u16* const sA1 = smem + 16384;
  u16* const sB0 = smem + 32768;                 // [192][64]
  u16* const sB1 = smem + 45056;

  const int tid = threadIdx.x, lane = tid & 63, w = tid >> 6;
  const int wr = w >> 2, wcn = w & 3;
  const int rl = lane & 15, g = lane >> 4, rsw = rl & 7;

  const int bflat = blockIdx.x;                  // 256 = 8 XCD * 32
  const int xcd = bflat & 7, idx = bflat >> 3;   // idx 0..31
  const int mt = xcd * 2 + (idx & 1);            // 16 m-tiles, 2 per XCD
  const int nt = idx >> 1;                       // 16 n-tiles of 192
  const int m0 = mt * 256;

  const int lr = lane >> 3, lc = lane & 7;
  const size_t srcoff = (size_t)(w * 8 + lr) * 1024 + ((lc ^ lr) * 8);
  const u16* gaS = X    + (size_t)m0 * 1024 + srcoff;
  const u16* gbS = Wqkv + (size_t)(nt * 192) * 1024 + srcoff;

  f32x4 acc[8][3];
#pragma unroll
  for (int mf = 0; mf < 8; ++mf)
#pragma unroll
    for (int nf = 0; nf < 3; ++nf) acc[mf][nf] = (f32x4){0.f, 0.f, 0.f, 0.f};

  auto loadA = [&](const u16* buf, int mf, int kh) -> short8 {
    return *(const short8*)&buf[(wr * 128 + mf * 16 + rl) * 64 +
                                (((kh * 4 + g) ^ rsw) * 8)];
  };
  auto loadB = [&](const u16* buf, int nf, int kh) -> short8 {
    return *(const short8*)&buf[(wcn * 48 + nf * 16 + rl) * 64 +
                                (((kh * 4 + g) ^ rsw) * 8)];
  };

  // one K-tile = 4 phases; stage halves of tile ts into stA/stB in ph0/ph1
  auto proc_tile = [&](const u16* bufA, const u16* bufB,
                       u16* stA, u16* stB, int ts, bool doSt) {
    short8 af[4], bf[3];
    // phase 0: stage A(next, 4 GLL) | B(kh0) + A(mf0-3,kh0) | 12 MFMA
    if (doSt) {
#pragma unroll
      for (int i = 0; i < 4; ++i)
        GLL16(gaS + (size_t)(i * 64) * 1024 + ts * 64, stA + (i * 64 + w * 8) * 64);
    }
#pragma unroll
    for (int nf = 0; nf < 3; ++nf) bf[nf] = loadB(bufB, nf, 0);
#pragma unroll
    for (int i = 0; i < 4; ++i) af[i] = loadA(bufA, i, 0);
    __builtin_amdgcn_s_setprio(1);
#pragma unroll
    for (int i = 0; i < 4; ++i)
#pragma unroll
      for (int nf = 0; nf < 3; ++nf)
        acc[i][nf] = mfma_bf16(af[i], bf[nf], acc[i][nf]);
    __builtin_amdgcn_s_setprio(0);
    __builtin_amdgcn_s_barrier();
    // phase 1: stage B(next, 3 GLL) | A(mf4-7,kh0) | 12 MFMA
    if (doSt) {
#pragma unroll
      for (int i = 0; i < 3; ++i)
        GLL16(gbS + (size_t)(i * 64) * 1024 + ts * 64, stB + (i * 64 + w * 8) * 64);
    }
#pragma unroll
    for (int i = 0; i < 4; ++i) af[i] = loadA(bufA, 4 + i, 0);
    __builtin_amdgcn_s_setprio(1);
#pragma unroll
    for (int i = 0; i < 4; ++i)
#pragma unroll
      for (int nf = 0; nf < 3; ++nf)
        acc[4 + i][nf] = mfma_bf16(af[i], bf[nf], acc[4 + i][nf]);
    __builtin_amdgcn_s_setprio(0);
    __builtin_amdgcn_s_barrier();
    // phase 2: B(kh1) + A(mf0-3,kh1) | 12 MFMA
#pragma unroll
    for (int nf = 0; nf < 3; ++nf) bf[nf] = loadB(bufB, nf, 1);
#pragma unroll
    for (int i = 0; i < 4; ++i) af[i] = loadA(bufA, i, 1);
    __builtin_amdgcn_s_setprio(1);
#pragma unroll
    for (int i = 0; i < 4; ++i)
#pragma unroll
      for (int nf = 0; nf < 3; ++nf)
        acc[i][nf] = mfma_bf16(af[i], bf[nf], acc[i][nf]);
    __builtin_amdgcn_s_setprio(0);
    __builtin_amdgcn_s_barrier();
    // phase 3: A(mf4-7,kh1) | 12 MFMA
#pragma unroll
    for (int i = 0; i < 4; ++i) af[i] = loadA(bufA, 4 + i, 1);
    __builtin_amdgcn_s_setprio(1);
#pragma unroll
    for (int i = 0; i < 4; ++i)
#pragma unroll
      for (int nf = 0; nf < 3; ++nf)
        acc[4 + i][nf] = mfma_bf16(af[i], bf[nf], acc[4 + i][nf]);
    __builtin_amdgcn_s_setprio(0);
  };

  // prologue: stage tile 0 into buf0
#pragma unroll
  for (int i = 0; i < 4; ++i)
    GLL16(gaS + (size_t)(i * 64) * 1024, sA0 + (i * 64 + w * 8) * 64);
#pragma unroll
  for (int i = 0; i < 3; ++i)
    GLL16(gbS + (size_t)(i * 64) * 1024, sB0 + (i * 64 + w * 8) * 64);
  __syncthreads();

#pragma unroll 1
  for (int tt = 0; tt < 8; ++tt) {
    proc_tile(sA0, sB0, sA1, sB1, 2 * tt + 1, true);
    __syncthreads();
    proc_tile(sA1, sB1, sA0, sB0, 2 * tt + 2, tt < 7);
    __syncthreads();
  }

  // -------- epilogue: per 16-col fragment, z = colg>>10 (uniform: 16-aligned)
  const int rg = g * 4;
#pragma unroll
  for (int nf = 0; nf < 3; ++nf) {
    const int colg = nt * 192 + wcn * 48 + nf * 16 + rl;   // 0..3071
    const int zc = colg >> 10;                             // 0=Q 1=K 2=V
    const int colp = colg & 1023;
    if (zc == 0) {
      float bb = bq[colp];
#pragma unroll
      for (int mf = 0; mf < 8; ++mf) {
        int row0 = m0 + wr * 128 + mf * 16 + rg;
#pragma unroll
        for (int r = 0; r < 4; ++r)
          Qo[(size_t)(row0 + r) * 1024 + colp] = f2bf((acc[mf][nf][r] + bb) * QSCALE);
      }
    } else if (zc == 1) {
      float bb = bk[colp];
#pragma unroll
      for (int mf = 0; mf < 8; ++mf) {
        int row0 = m0 + wr * 128 + mf * 16 + rg;
#pragma unroll
        for (int r = 0; r < 4; ++r)
          Ko[(size_t)(row0 + r) * 1024 + colp] = f2bf(acc[mf][nf][r] + bb);
      }
    } else {
      float bb = bv[colp];
#pragma unroll
      for (int mf = 0; mf < 8; ++mf) {
        int row0 = m0 + wr * 128 + mf * 16 + rg;       // b*2048 + s
        int bidx = row0 >> 11, sl = row0 & 2047;
        u16x4 pk;
#pragma unroll
        for (int r = 0; r < 4; ++r) pk[r] = f2bf(acc[mf][nf][r] + bb);
        *(u16x4*)&Vt[((size_t)(bidx * 1024 + colp)) * 2048 + sl] = pk;
      }
    }
  }
}

// Output projection: out(fp32) = Ob @ Wo^T + bo. 64x128 tiles -> 512 blocks
// (2 blocks/CU); xcd = b&7 owns m-tiles {8x..8x+7} (R13-proven version).
__global__ __launch_bounds__(256) void gemm_out(
    const u16* __restrict__ Ob, const u16* __restrict__ Wob,
    const float* __restrict__ bo, float* __restrict__ Out)
{
  __shared__ u16 sA[2048], sB[4096];
  const int bflat = blockIdx.x;
  const int xcd = bflat & 7, idx = bflat >> 3;      // idx 0..63
  const int m0 = (xcd * 8 + (idx & 7)) * 64;
  const int n0 = (idx >> 3) * 128;

  const int tid = threadIdx.x, lane = tid & 63, wave = tid >> 6;
  const int wr = wave >> 1, wc = wave & 1;
  const u16* ga = Ob  + (size_t)(m0 + (tid >> 2)) * 1024 + (tid & 3) * 8;
  const u16* gb = Wob + (size_t)(n0 + (tid >> 2)) * 1024 + (tid & 3) * 8;
  u16* la0 = sA + wave * 512;
  u16* lb0 = sB + wave * 512;          u16* lb1 = sB + 2048 + wave * 512;
  const int rl = lane & 15, kg = (lane >> 4) * 8, rg = (lane >> 4) * 4;

  f32x4 acc[2][4];
#pragma unroll
  for (int m = 0; m < 2; ++m)
#pragma unroll
    for (int n = 0; n < 4; ++n) acc[m][n] = (f32x4){0.f, 0.f, 0.f, 0.f};

  for (int k0 = 0; k0 < 1024; k0 += 32) {
    GLL16(ga + k0,             la0);   // A 64x32 (rows tid>>2)
    GLL16(gb + k0,             lb0);   // B rows 0..63
    GLL16(gb + 64 * 1024 + k0, lb1);   // B rows 64..127
    __syncthreads();
    short8 af[2], bf_[4];
#pragma unroll
    for (int m = 0; m < 2; ++m) af[m]  = *(const short8*)&sA[(wr * 32 + m * 16 + rl) * 32 + kg];
#pragma unroll
    for (int n = 0; n < 4; ++n) bf_[n] = *(const short8*)&sB[(wc * 64 + n * 16 + rl) * 32 + kg];
#pragma unroll
    for (int m = 0; m < 2; ++m)
#pragma unroll
      for (int n = 0; n < 4; ++n)
        acc[m][n] = mfma_bf16(af[m], bf_[n], acc[m][n]);
    __syncthreads();
  }

#pragma unroll
  for (int n = 0; n < 4; ++n) {
    int col = n0 + wc * 64 + n * 16 + rl;
    float bb = bo[col];
#pragma unroll
    for (int m = 0; m < 2; ++m) {
      int row0 = m0 + wr * 32 + m * 16 + rg;
#pragma unroll
      for (int r = 0; r < 4; ++r)
        Out[(size_t)(row0 + r) * 1024 + col] = acc[m][n][r] + bb;
    }
  }
}

// ---------------------------------------------------------------- flash attention
// R6 kernel exact (proven 48.0us, 0 bank conflicts). Swapped QK^T (mfma(K,Q));
// K rows read PERMUTED from LDS so score C-regs match PV B-operand k-order;
// Q pre-scaled by 0.125*log2e. K/V staged per 64-key tile into double-buffered
// XOR-swizzled LDS via global_load_lds. Wave = 16 q rows; block = 8 waves
// (512 thr); grid = 512; XCD x owns bh {4x..4x+3} (2MB K/V in its L2).
__global__ __launch_bounds__(512) void attn_fwd(
    const u16* __restrict__ Q, const u16* __restrict__ K,
    const u16* __restrict__ Vt, u16* __restrict__ O)
{
  __shared__ u16 sK[2][64][64];   // [buf][key row][d elems], elem-swizzled
  __shared__ u16 sV[2][64][64];   // [buf][d row][key elems], elem-swizzled

  const int tid = threadIdx.x, lane = tid & 63, wave = tid >> 6;  // wave 0..7
  const int rl = lane & 15, g = lane >> 4;

  const int bflat = blockIdx.x;
  const int xcd = bflat & 7, j = bflat >> 3;        // 512 = 8 XCD * 64
  const int bh = xcd * 4 + (j >> 4);                // 4 bh per XCD (2MB in L2)
  const int qchunk = j & 15;
  const int b = bh >> 4, h = bh & 15;
  const int qbase = qchunk * 128 + wave * 16;

  const u16* Qp = Q + (size_t)(b * 2048 + qbase) * 1024 + h * 64;
  const u16* Kp = K + (size_t)(b * 2048) * 1024 + h * 64;
  const u16* Vp = Vt + (size_t)(bh * 64) * 2048;

  short8 qf[2];
#pragma unroll
  for (int hf = 0; hf < 2; ++hf)
    qf[hf] = *(const short8*)&Qp[(size_t)rl * 1024 + hf * 32 + g * 8];

  const int keyperm = 8 * (rl >> 2) + (rl & 3);
  // K read swizzle (elements): swzK(r) = (r&3)|(((r>>3)&1)<<2); r bits from rl only
  const int swzK8 = (((rl & 3) | (((rl >> 2) & 1) << 2))) * 8;
  // V read swizzle: swzV(r) = r&7 with r = dg*16+rl -> rl&7
  const int swzV8 = (rl & 7) * 8;

  // staging address precompute (thread-constant); chunk = wave (0..7)
  const int srow = lane >> 3;                       // row within 8-row chunk
  const int feK = (((lane & 7) ^ (srow & 3)) * 8) ^ ((wave & 1) * 32);
  const int feV = (((lane & 7) ^ srow) * 8);

  f32x4 oacc[4];
  f32x4 lacc = (f32x4){0.f, 0.f, 0.f, 0.f};
#pragma unroll
  for (int dg = 0; dg < 4; ++dg) oacc[dg] = (f32x4){0.f, 0.f, 0.f, 0.f};
  float mrun = -INFINITY;

  const short8 ONES = {0x3F80, 0x3F80, 0x3F80, 0x3F80,
                       0x3F80, 0x3F80, 0x3F80, 0x3F80};  // bf16 1.0 x8

  // stage one 64-key tile (K 8KB + V 8KB) into buffer nb; 1 GLL each per thread
  auto stage = [&](int nb, int kt) {
    const int grow = wave * 8 + srow;               // 0..63
    GLL16(Kp + (size_t)(kt + grow) * 1024 + feK, &sK[nb][wave * 8][0]);
    GLL16(Vp + (size_t)grow * 2048 + kt + feV,   &sV[nb][wave * 8][0]);
  };

  // process one 32-key subtile from buffer nb
  auto proc_sub = [&](int nb, int sub) {
    short8 kf[2][2];
#pragma unroll
    for (int t = 0; t < 2; ++t) {
      const int r = sub * 32 + keyperm + 4 * t;
#pragma unroll
      for (int hf = 0; hf < 2; ++hf)
        kf[t][hf] = *(const short8*)&sK[nb][r][(hf * 32 + g * 8) ^ swzK8];
    }
    short8 vf[4];
#pragma unroll
    for (int dg = 0; dg < 4; ++dg)
      vf[dg] = *(const short8*)&sV[nb][dg * 16 + rl][(sub * 32 + g * 8) ^ swzV8];

    f32x4 sc[2];
    __builtin_amdgcn_s_setprio(1);
#pragma unroll
    for (int t = 0; t < 2; ++t) {
      f32x4 a = (f32x4){0.f, 0.f, 0.f, 0.f};
      a = mfma_bf16(kf[t][0], qf[0], a);
      a = mfma_bf16(kf[t][1], qf[1], a);
      sc[t] = a;
    }
    __builtin_amdgcn_s_setprio(0);

    float p2[8];
#pragma unroll
    for (int t = 0; t < 2; ++t)
#pragma unroll
      for (int r = 0; r < 4; ++r) p2[t * 4 + r] = sc[t][r];
    float a0 = fmaxf(fmaxf(p2[0], p2[1]), p2[2]);
    float a1 = fmaxf(fmaxf(p2[3], p2[4]), p2[5]);
    float a2 = fmaxf(p2[6], p2[7]);
    float tm = fmaxf(fmaxf(a0, a1), a2);
    // defer-max: rescale only when tile max grows past THR=8 (exp2 domain)
    if (!__all(tm <= mrun + 8.0f)) {
      tm = fmaxf(tm, __shfl_xor(tm, 16));
      tm = fmaxf(tm, __shfl_xor(tm, 32));
      float mnew = fmaxf(mrun, tm);
      float sfac = __builtin_amdgcn_exp2f(mrun - mnew);
      mrun = mnew;
#pragma unroll
      for (int dg = 0; dg < 4; ++dg)
#pragma unroll
        for (int r = 0; r < 4; ++r) oacc[dg][r] *= sfac;
      lacc[0] *= sfac;   // only reg 0 is ever read
    }
    short8 pb;
#pragma unroll
    for (int j2 = 0; j2 < 8; ++j2)
      pb[j2] = (short)f2bf(__builtin_amdgcn_exp2f(p2[j2] - mrun));

    __builtin_amdgcn_s_setprio(1);
    lacc = mfma_bf16(ONES, pb, lacc);   // row-sum on matrix pipe
#pragma unroll
    for (int dg = 0; dg < 4; ++dg)
      oacc[dg] = mfma_bf16(vf[dg], pb, oacc[dg]);
    __builtin_amdgcn_s_setprio(0);
  };

  // double-buffered main loop: 32 tiles of 64 keys, unrolled x2 (static nb)
  stage(0, 0);
  __syncthreads();
  for (int kt = 0; kt < 2048; kt += 128) {
    stage(1, kt + 64);
    proc_sub(0, 0);
    proc_sub(0, 1);
    __syncthreads();                     // buf1 staged; buf0 fully read
    if (kt + 128 < 2048) stage(0, kt + 128);
    proc_sub(1, 0);
    proc_sub(1, 1);
    __syncthreads();
  }

  float inv = 1.0f / lacc[0];
  int qrow = qbase + rl;
  u16* op = O + (size_t)(b * 2048 + qrow) * 1024 + h * 64;
#pragma unroll
  for (int dg = 0; dg < 4; ++dg) {
    u16x4 pk;
#pragma unroll
    for (int r = 0; r < 4; ++r) pk[r] = f2bf(oacc[dg][r] * inv);
    *(u16x4*)&op[dg * 16 + g * 4] = pk;
  }
}

// ---------------------------------------------------------------- launch
extern "C" void kernel_launch(void* const* d_in, const int* in_sizes, int n_in,
                              void* d_out, int out_size, void* d_ws, size_t ws_size,
                              hipStream_t stream) {
  const float* x  = (const float*)d_in[0];
  const float* Wq = (const float*)d_in[1];
  const float* bq = (const float*)d_in[2];
  const float* Wk = (const float*)d_in[3];
  const float* bk = (const float*)d_in[4];
  const float* Wv = (const float*)d_in[5];
  const float* bv = (const float*)d_in[6];
  const float* Wo = (const float*)d_in[7];
  const float* bo = (const float*)d_in[8];

  char* ws = (char*)d_ws;
  const size_t MB = 1024 * 1024;
  u16* Xb  = (u16*)(ws + 0 * MB);
  u16* Wqb = (u16*)(ws + 8 * MB);    // Wqkv|Wo: 4 contiguous 2MB panels
  u16* Wob = (u16*)(ws + 14 * MB);
  u16* Qb  = (u16*)(ws + 16 * MB);
  u16* Kb  = (u16*)(ws + 24 * MB);
  u16* Vtb = (u16*)(ws + 32 * MB);
  u16* Ob  = (u16*)(ws + 40 * MB);

  cast_all<<<dim3(8192), 256, 0, stream>>>(x, Wq, Wk, Wv, Wo, Xb, Wqb);
  gemm_qkv<<<dim3(256), 512, 0, stream>>>(Xb, Wqb, bq, bk, bv, Qb, Kb, Vtb);
  attn_fwd<<<dim3(512), 512, 0, stream>>>(Qb, Kb, Vtb, Ob);
  gemm_out<<<dim3(512), 256, 0, stream>>>(Ob, Wob, bo, (float*)d_out);
}